// Round 1
// 339.726 us; speedup vs baseline: 1.1947x; 1.1947x over previous
//
#include <hip/hip_runtime.h>
#include <math.h>

// Problem constants: B=4, N=4096, D_in=256, D_out=128
#define NTOK 4096
#define RTOT 16384   // B*N
#define DIN  256
#define DOUT 128

constexpr float LEAKY = 0.01f;
constexpr float THR   = 0.1f;

typedef __attribute__((ext_vector_type(8)))  short bf16x8;   // 8 bf16 = 4 VGPRs
typedef __attribute__((ext_vector_type(16))) float f32x16;   // mfma 32x32 acc

// round-to-nearest-even f32 -> bf16 (bit pattern)
__device__ __forceinline__ unsigned short f2bf(float x) {
    unsigned u = __float_as_uint(x);
    unsigned r = (u + 0x7fffu + ((u >> 16) & 1u)) >> 16;
    return (unsigned short)r;
}
__device__ __forceinline__ float bf2f(unsigned short h) {
    return __uint_as_float((unsigned)h << 16);
}

// ---------------------------------------------------------------------------
// Kernel 1: H = leaky_relu(A @ W); row-normalize; emit split-bf16 Hhi/Hlo.
// hn = h / ||h||  (so dots of hn ARE cosines; eps branch is dead: norms ~ 8)
// Hhi = bf16(hn), Hlo = bf16(hn - Hhi)  -> 3-product GEMM gives ~1e-7 accuracy
// ---------------------------------------------------------------------------
__global__ __launch_bounds__(256, 2) void proj_kernel(
    const float* __restrict__ A, const float* __restrict__ W,
    unsigned short* __restrict__ Hhi, unsigned short* __restrict__ Hlo)
{
    __shared__ float As[32 * DIN];    // 32 KB
    __shared__ float Ws[64 * DOUT];   // 32 KB
    const int tid  = threadIdx.x;
    const int row0 = blockIdx.x * 32;

    {
        const float4* src = (const float4*)(A + (size_t)row0 * DIN);
        float4* dst = (float4*)As;
        #pragma unroll
        for (int it = 0; it < 8; ++it)
            dst[tid + it * 256] = src[tid + it * 256];
    }

    const int tx = tid & 31;
    const int ty = tid >> 5;

    float acc[4][4];
    #pragma unroll
    for (int i = 0; i < 4; ++i)
        #pragma unroll
        for (int j = 0; j < 4; ++j) acc[i][j] = 0.f;

    for (int kc = 0; kc < DIN; kc += 64) {
        __syncthreads();
        {
            const float4* wsrc = (const float4*)(W + (size_t)kc * DOUT);
            float4* wdst = (float4*)Ws;
            #pragma unroll
            for (int it = 0; it < 8; ++it)
                wdst[tid + it * 256] = wsrc[tid + it * 256];
        }
        __syncthreads();

        for (int k = 0; k < 64; k += 4) {
            float4 w4[4];
            #pragma unroll
            for (int s = 0; s < 4; ++s)
                w4[s] = *(const float4*)(Ws + (k + s) * DOUT + 4 * tx);
            #pragma unroll
            for (int i = 0; i < 4; ++i) {
                float4 a4 = *(const float4*)(As + (ty + 8 * i) * DIN + kc + k);
                float ak[4] = {a4.x, a4.y, a4.z, a4.w};
                #pragma unroll
                for (int s = 0; s < 4; ++s) {
                    float wj[4] = {w4[s].x, w4[s].y, w4[s].z, w4[s].w};
                    #pragma unroll
                    for (int j = 0; j < 4; ++j)
                        acc[i][j] = fmaf(ak[s], wj[j], acc[i][j]);
                }
            }
        }
    }

    #pragma unroll
    for (int i = 0; i < 4; ++i) {
        float h[4];
        float s = 0.f;
        #pragma unroll
        for (int j = 0; j < 4; ++j) {
            float v = acc[i][j];
            h[j] = (v >= 0.f) ? v : LEAKY * v;
            s = fmaf(h[j], h[j], s);
        }
        // butterfly: every lane of the 32-lane half gets the full row sumsq
        #pragma unroll
        for (int m = 16; m >= 1; m >>= 1)
            s += __shfl_xor(s, m, 64);
        const float rinv = 1.0f / sqrtf(s);
        const int r = row0 + ty + 8 * i;
        ushort4 hv, lv;
        {
            float n0 = h[0] * rinv; hv.x = f2bf(n0); lv.x = f2bf(n0 - bf2f(hv.x));
            float n1 = h[1] * rinv; hv.y = f2bf(n1); lv.y = f2bf(n1 - bf2f(hv.y));
            float n2 = h[2] * rinv; hv.z = f2bf(n2); lv.z = f2bf(n2 - bf2f(hv.z));
            float n3 = h[3] * rinv; hv.w = f2bf(n3); lv.w = f2bf(n3 - bf2f(hv.w));
        }
        *(ushort4*)(Hhi + (size_t)r * DOUT + 4 * tx) = hv;
        *(ushort4*)(Hlo + (size_t)r * DOUT + 4 * tx) = lv;
    }
}

// ---------------------------------------------------------------------------
// Kernel 2: cos tile GEMM on the matrix pipe.
// Full 32x32 grid of 128x128 tiles (no triangular/mirror: MFMA compute ~5us).
// 4 waves as 2x2 quadrants; each wave owns 64x64 = 2x2 mfma_32x32x16 tiles.
// acc += Ahi*Bhi + Ahi*Blo + Alo*Bhi   (fp32 accum)
// LDS: per matrix [128 rows][4 slots of 16B], slot ^= (row&3) swizzle so both
// staging ds_write_b128 and fragment ds_read_b128 sit at the 8-lane/bank-quad
// structural floor (naive layout would be 16-way conflicted).
// ---------------------------------------------------------------------------
__global__ __launch_bounds__(256, 4) void cos_kernel(
    const unsigned short* __restrict__ Hhi,
    const unsigned short* __restrict__ Hlo,
    float* __restrict__ out)
{
    __shared__ uint4 smem4[2048];        // 32 KB: [Ahi|Alo|Bhi|Blo], 8KB each
    char* smem = (char*)smem4;

    const int b  = blockIdx.y;
    const int ti = (blockIdx.x >> 5) << 7;    // row tile base (token)
    const int tj = (blockIdx.x & 31) << 7;    // col tile base (token)
    const int bN = b * NTOK;

    const int tid  = threadIdx.x;
    const int wave = tid >> 6;
    const int lane = tid & 63;
    const int qr = wave & 1;           // row quadrant (0..1)
    const int qc = wave >> 1;          // col quadrant (0..1)
    const int lr = lane & 31;          // mfma operand row within 32-tile
    const int hh = lane >> 5;          // k-slot half selector

    f32x16 acc[2][2];
    #pragma unroll
    for (int i = 0; i < 2; ++i)
        #pragma unroll
        for (int j = 0; j < 2; ++j)
            #pragma unroll
            for (int e = 0; e < 16; ++e)
                acc[i][j][e] = 0.f;

    for (int kc = 0; kc < DOUT; kc += 32) {
        __syncthreads();
        // Stage 32 KB = 2048 x 16B units; 8 per thread, in 2 rounds of 4
        // (limits live VGPRs). Unit u: m=matrix, r=row 0..127, sl=frag slot.
        #pragma unroll
        for (int half = 0; half < 2; ++half) {
            uint4 v[4];
            int   d[4];
            #pragma unroll
            for (int q = 0; q < 4; ++q) {
                const int u  = (half * 4 + q) * 256 + tid;
                const int m  = u >> 9;         // 0:Ahi 1:Alo 2:Bhi 3:Blo (wave-uniform)
                const int w  = u & 511;
                const int r  = w >> 2;
                const int sl = w & 3;
                const unsigned short* src = (m & 1) ? Hlo : Hhi;
                const int rb = (m < 2) ? ti : tj;
                v[q] = *(const uint4*)(src + (((size_t)(bN + rb + r)) << 7)
                                           + kc + (sl << 3));
                d[q] = (m << 13) + (r << 6) + ((sl ^ (r & 3)) << 4);
            }
            #pragma unroll
            for (int q = 0; q < 4; ++q)
                *(uint4*)(smem + d[q]) = v[q];
        }
        __syncthreads();

        #pragma unroll
        for (int ks = 0; ks < 2; ++ks) {
            bf16x8 ah[2], al[2], bh[2], bl[2];
            const int s = (ks << 1) | hh;     // frag slot: k = kc + 8*s .. +8
            #pragma unroll
            for (int t = 0; t < 2; ++t) {
                const int ra = qr * 64 + t * 32 + lr;
                const int oa = (ra << 6) + ((s ^ (ra & 3)) << 4);
                ah[t] = *(const bf16x8*)(smem + oa);
                al[t] = *(const bf16x8*)(smem + 8192 + oa);
                const int rb = qc * 64 + t * 32 + lr;
                const int ob = (rb << 6) + ((s ^ (rb & 3)) << 4);
                bh[t] = *(const bf16x8*)(smem + 16384 + ob);
                bl[t] = *(const bf16x8*)(smem + 24576 + ob);
            }
            #pragma unroll
            for (int i = 0; i < 2; ++i)
                #pragma unroll
                for (int j = 0; j < 2; ++j) {
                    acc[i][j] = __builtin_amdgcn_mfma_f32_32x32x16_bf16(
                                    ah[i], bh[j], acc[i][j], 0, 0, 0);
                    acc[i][j] = __builtin_amdgcn_mfma_f32_32x32x16_bf16(
                                    ah[i], bl[j], acc[i][j], 0, 0, 0);
                    acc[i][j] = __builtin_amdgcn_mfma_f32_32x32x16_bf16(
                                    al[i], bh[j], acc[i][j], 0, 0, 0);
                }
        }
    }

    // Epilogue: abs + threshold, direct coalesced stores.
    // C/D layout (32x32x16): col = lane&31, row = (v&3) + 8*(v>>2) + 4*(lane>>5)
    float* Ob = out + (size_t)b * NTOK * NTOK;
    const int col = tj + qc * 64 + lr;
    #pragma unroll
    for (int i = 0; i < 2; ++i) {
        const int rbase = ti + qr * 64 + i * 32 + (hh << 2);
        #pragma unroll
        for (int j = 0; j < 2; ++j) {
            const int c = col + j * 32;
            #pragma unroll
            for (int v = 0; v < 16; ++v) {
                const int row = rbase + (v & 3) + ((v >> 2) << 3);
                float x = fabsf(acc[i][j][v]);
                x = (x > THR) ? x : 0.f;
                Ob[(size_t)row * NTOK + c] = x;
            }
        }
    }
}

extern "C" void kernel_launch(void* const* d_in, const int* in_sizes, int n_in,
                              void* d_out, int out_size, void* d_ws, size_t ws_size,
                              hipStream_t stream) {
    const float* A = (const float*)d_in[0];   // [4,4096,256]
    const float* W = (const float*)d_in[1];   // [256,128]
    float* out = (float*)d_out;               // [4,4096,4096]

    unsigned short* Hhi = (unsigned short*)d_ws;            // 4 MB
    unsigned short* Hlo = Hhi + (size_t)RTOT * DOUT;        // 4 MB

    proj_kernel<<<RTOT / 32, 256, 0, stream>>>(A, W, Hhi, Hlo);
    cos_kernel<<<dim3(1024, 4), 256, 0, stream>>>(Hhi, Hlo, out);
}

// Round 2
// 327.697 us; speedup vs baseline: 1.2385x; 1.0367x over previous
//
#include <hip/hip_runtime.h>
#include <math.h>

// Problem constants: B=4, N=4096, D_in=256, D_out=128
#define NTOK 4096
#define RTOT 16384   // B*N
#define DIN  256
#define DOUT 128

constexpr float LEAKY = 0.01f;
constexpr float THR   = 0.1f;

typedef __attribute__((ext_vector_type(8)))  short bf16x8;   // 8 bf16 = 4 VGPRs
typedef __attribute__((ext_vector_type(16))) float f32x16;   // mfma 32x32 acc

// round-to-nearest-even f32 -> bf16 (bit pattern)
__device__ __forceinline__ unsigned short f2bf(float x) {
    unsigned u = __float_as_uint(x);
    unsigned r = (u + 0x7fffu + ((u >> 16) & 1u)) >> 16;
    return (unsigned short)r;
}
__device__ __forceinline__ float bf2f(unsigned short h) {
    return __uint_as_float((unsigned)h << 16);
}

// async global->LDS, 16B per lane. LDS dest is wave-uniform base + lane*16.
__device__ __forceinline__ void gload_lds16(const void* g, void* l) {
    __builtin_amdgcn_global_load_lds(
        (const __attribute__((address_space(1))) void*)g,
        (__attribute__((address_space(3))) void*)l,
        16, 0, 0);
}

// ---------------------------------------------------------------------------
// Kernel 1: H = leaky_relu(A @ W); row-normalize; emit split-bf16 Hhi/Hlo.
// hn = h / ||h||  (so dots of hn ARE cosines; eps branch is dead: norms ~ 8)
// Hhi = bf16(hn), Hlo = bf16(hn - Hhi)  -> 3-product GEMM gives ~1e-7 accuracy
// ---------------------------------------------------------------------------
__global__ __launch_bounds__(256, 2) void proj_kernel(
    const float* __restrict__ A, const float* __restrict__ W,
    unsigned short* __restrict__ Hhi, unsigned short* __restrict__ Hlo)
{
    __shared__ float As[32 * DIN];    // 32 KB
    __shared__ float Ws[64 * DOUT];   // 32 KB
    const int tid  = threadIdx.x;
    const int row0 = blockIdx.x * 32;

    {
        const float4* src = (const float4*)(A + (size_t)row0 * DIN);
        float4* dst = (float4*)As;
        #pragma unroll
        for (int it = 0; it < 8; ++it)
            dst[tid + it * 256] = src[tid + it * 256];
    }

    const int tx = tid & 31;
    const int ty = tid >> 5;

    float acc[4][4];
    #pragma unroll
    for (int i = 0; i < 4; ++i)
        #pragma unroll
        for (int j = 0; j < 4; ++j) acc[i][j] = 0.f;

    for (int kc = 0; kc < DIN; kc += 64) {
        __syncthreads();
        {
            const float4* wsrc = (const float4*)(W + (size_t)kc * DOUT);
            float4* wdst = (float4*)Ws;
            #pragma unroll
            for (int it = 0; it < 8; ++it)
                wdst[tid + it * 256] = wsrc[tid + it * 256];
        }
        __syncthreads();

        for (int k = 0; k < 64; k += 4) {
            float4 w4[4];
            #pragma unroll
            for (int s = 0; s < 4; ++s)
                w4[s] = *(const float4*)(Ws + (k + s) * DOUT + 4 * tx);
            #pragma unroll
            for (int i = 0; i < 4; ++i) {
                float4 a4 = *(const float4*)(As + (ty + 8 * i) * DIN + kc + k);
                float ak[4] = {a4.x, a4.y, a4.z, a4.w};
                #pragma unroll
                for (int s = 0; s < 4; ++s) {
                    float wj[4] = {w4[s].x, w4[s].y, w4[s].z, w4[s].w};
                    #pragma unroll
                    for (int j = 0; j < 4; ++j)
                        acc[i][j] = fmaf(ak[s], wj[j], acc[i][j]);
                }
            }
        }
    }

    #pragma unroll
    for (int i = 0; i < 4; ++i) {
        float h[4];
        float s = 0.f;
        #pragma unroll
        for (int j = 0; j < 4; ++j) {
            float v = acc[i][j];
            h[j] = (v >= 0.f) ? v : LEAKY * v;
            s = fmaf(h[j], h[j], s);
        }
        #pragma unroll
        for (int m = 16; m >= 1; m >>= 1)
            s += __shfl_xor(s, m, 64);
        const float rinv = 1.0f / sqrtf(s);
        const int r = row0 + ty + 8 * i;
        ushort4 hv, lv;
        {
            float n0 = h[0] * rinv; hv.x = f2bf(n0); lv.x = f2bf(n0 - bf2f(hv.x));
            float n1 = h[1] * rinv; hv.y = f2bf(n1); lv.y = f2bf(n1 - bf2f(hv.y));
            float n2 = h[2] * rinv; hv.z = f2bf(n2); lv.z = f2bf(n2 - bf2f(hv.z));
            float n3 = h[3] * rinv; hv.w = f2bf(n3); lv.w = f2bf(n3 - bf2f(hv.w));
        }
        *(ushort4*)(Hhi + (size_t)r * DOUT + 4 * tx) = hv;
        *(ushort4*)(Hlo + (size_t)r * DOUT + 4 * tx) = lv;
    }
}

// ---------------------------------------------------------------------------
// Kernel 2: cos tile GEMM on the matrix pipe.
// acc += Ahi*Bhi + Ahi*Blo + Alo*Bhi   (fp32 accum), 128x128 tile per block.
//
// Staging now uses global_load_lds width=16 (no VGPR round-trip): LDS dest is
// LINEAR per-lane (HW requirement, m104); the slot-XOR swizzle is applied to
// the per-lane GLOBAL source address instead (m173 pattern).  Wave w owns
// section w (0:Ahi 1:Alo 2:Bhi 3:Blo, 8KB each).  For inst it, lane l:
//   unit ui = it*64+l -> row r = it*16 + (l>>2), lds slot sl' = l&3,
//   global slot sl = sl' ^ (r&3) = (l&3) ^ ((l>>2)&3)   (it-invariant!)
// Compute-side reads (slot s^(row&3)) are unchanged and see global slot s.
//
// Output stores are NONTEMPORAL: 268 MB write-once stream must not allocate
// in L2/L3 (which also serves the H-panel re-reads).
// ---------------------------------------------------------------------------
__global__ __launch_bounds__(256, 4) void cos_kernel(
    const unsigned short* __restrict__ Hhi,
    const unsigned short* __restrict__ Hlo,
    float* __restrict__ out)
{
    __shared__ uint4 smem4[2048];        // 32 KB: [Ahi|Alo|Bhi|Blo], 8KB each
    char* smem = (char*)smem4;

    const int b  = blockIdx.y;
    const int ti = (blockIdx.x >> 5) << 7;    // row tile base (token)
    const int tj = (blockIdx.x & 31) << 7;    // col tile base (token)
    const int bN = b * NTOK;

    const int tid  = threadIdx.x;
    const int wave = tid >> 6;
    const int lane = tid & 63;
    const int qr = wave & 1;           // row quadrant (0..1)
    const int qc = wave >> 1;          // col quadrant (0..1)
    const int lr = lane & 31;          // mfma operand row within 32-tile
    const int hh = lane >> 5;          // k-slot half selector

    // per-lane staging source (elements); section chosen by wave
    const unsigned short* gbase =
        ((wave & 1) ? Hlo : Hhi)
        + (((size_t)(bN + ((wave >> 1) ? tj : ti) + (lane >> 2))) << 7)
        + ((size_t)(((lane & 3) ^ ((lane >> 2) & 3)) << 3));
    char* lbase = smem + (wave << 13);   // wave-uniform section base

    f32x16 acc[2][2];
    #pragma unroll
    for (int i = 0; i < 2; ++i)
        #pragma unroll
        for (int j = 0; j < 2; ++j)
            #pragma unroll
            for (int e = 0; e < 16; ++e)
                acc[i][j][e] = 0.f;

    for (int kc = 0; kc < DOUT; kc += 32) {
        __syncthreads();
        #pragma unroll
        for (int it = 0; it < 8; ++it)
            gload_lds16(gbase + kc + it * 2048, lbase + (it << 10));
        __syncthreads();   // compiler emits vmcnt(0) drain before s_barrier

        #pragma unroll
        for (int ks = 0; ks < 2; ++ks) {
            bf16x8 ah[2], al[2], bh[2], bl[2];
            const int s = (ks << 1) | hh;     // frag slot: k = kc + 8*s .. +8
            #pragma unroll
            for (int t = 0; t < 2; ++t) {
                const int ra = qr * 64 + t * 32 + lr;
                const int oa = (ra << 6) + ((s ^ (ra & 3)) << 4);
                ah[t] = *(const bf16x8*)(smem + oa);
                al[t] = *(const bf16x8*)(smem + 8192 + oa);
                const int rb = qc * 64 + t * 32 + lr;
                const int ob = (rb << 6) + ((s ^ (rb & 3)) << 4);
                bh[t] = *(const bf16x8*)(smem + 16384 + ob);
                bl[t] = *(const bf16x8*)(smem + 24576 + ob);
            }
            #pragma unroll
            for (int i = 0; i < 2; ++i)
                #pragma unroll
                for (int j = 0; j < 2; ++j) {
                    acc[i][j] = __builtin_amdgcn_mfma_f32_32x32x16_bf16(
                                    ah[i], bh[j], acc[i][j], 0, 0, 0);
                    acc[i][j] = __builtin_amdgcn_mfma_f32_32x32x16_bf16(
                                    ah[i], bl[j], acc[i][j], 0, 0, 0);
                    acc[i][j] = __builtin_amdgcn_mfma_f32_32x32x16_bf16(
                                    al[i], bh[j], acc[i][j], 0, 0, 0);
                }
        }
    }

    // Epilogue: abs + threshold, nontemporal coalesced stores.
    // C/D layout (32x32x16): col = lane&31, row = (v&3) + 8*(v>>2) + 4*(lane>>5)
    float* Ob = out + (size_t)b * NTOK * NTOK;
    const int col = tj + qc * 64 + lr;
    #pragma unroll
    for (int i = 0; i < 2; ++i) {
        const int rbase = ti + qr * 64 + i * 32 + (hh << 2);
        #pragma unroll
        for (int j = 0; j < 2; ++j) {
            const int c = col + j * 32;
            #pragma unroll
            for (int v = 0; v < 16; ++v) {
                const int row = rbase + (v & 3) + ((v >> 2) << 3);
                float x = fabsf(acc[i][j][v]);
                x = (x > THR) ? x : 0.f;
                __builtin_nontemporal_store(x, Ob + (size_t)row * NTOK + c);
            }
        }
    }
}

extern "C" void kernel_launch(void* const* d_in, const int* in_sizes, int n_in,
                              void* d_out, int out_size, void* d_ws, size_t ws_size,
                              hipStream_t stream) {
    const float* A = (const float*)d_in[0];   // [4,4096,256]
    const float* W = (const float*)d_in[1];   // [256,128]
    float* out = (float*)d_out;               // [4,4096,4096]

    unsigned short* Hhi = (unsigned short*)d_ws;            // 4 MB
    unsigned short* Hlo = Hhi + (size_t)RTOT * DOUT;        // 4 MB

    proj_kernel<<<RTOT / 32, 256, 0, stream>>>(A, W, Hhi, Hlo);
    cos_kernel<<<dim3(1024, 4), 256, 0, stream>>>(Hhi, Hlo, out);
}